// Round 2
// baseline (406.685 us; speedup 1.0000x reference)
//
#include <hip/hip_runtime.h>
#include <cstdint>
#include <cstddef>

// Problem constants (Learnable_32650341384420)
#define HH 1024      // H (channels)
#define LL 8192      // L (sequence)
#define NB 4         // B (batch)
#define KD 64
#define KLEN 512     // KD * 2^(NS-1)

typedef float v4f  __attribute__((ext_vector_type(4)));
typedef float v16f __attribute__((ext_vector_type(16)));
typedef short v8s  __attribute__((ext_vector_type(8)));

__device__ __forceinline__ unsigned short f2bf(float f) {
  union { float f; unsigned int u; } x; x.f = f;
  unsigned int r = x.u + 0x7fffu + ((x.u >> 16) & 1u);
  return (unsigned short)(r >> 16);
}

// ---------------------------------------------------------------------------
// K1: build normalized 512-tap kernel per h (fp32).
// ---------------------------------------------------------------------------
__global__ __launch_bounds__(512) void build_k_kernel(
    const float* __restrict__ k0, const float* __restrict__ k1,
    const float* __restrict__ k2, const float* __restrict__ k3,
    float* __restrict__ kout) {
  __shared__ float lk[4][KD];
  __shared__ float red[512];
  const int h = blockIdx.x;
  const int t = threadIdx.x;
  if (t < 256) {
    int i = t >> 6, j = t & 63;
    const float* src = (i == 0) ? k0 : (i == 1) ? k1 : (i == 2) ? k2 : k3;
    lk[i][j] = src[h * KD + j];
  }
  __syncthreads();
  float kt = 0.f;
#pragma unroll
  for (int i = 0; i < 4; i++) {
    int len = KD << i;
    if (t < len) {
      float inv = 1.0f / (float)(1 << i);
      float c = ((float)t + 0.5f) * inv - 0.5f;
      c = fminf(fmaxf(c, 0.0f), 63.0f);
      int lo = (int)floorf(c);
      int hi = min(lo + 1, 63);
      float w = c - (float)lo;
      float v = lk[i][lo] * (1.0f - w) + lk[i][hi] * w;
      kt += v * (float)(1 << (3 - i));
    }
  }
  red[t] = kt * kt;
  __syncthreads();
  for (int s = 256; s > 0; s >>= 1) {
    if (t < s) red[t] += red[t + s];
    __syncthreads();
  }
  float norm = sqrtf(red[0]);
  kout[h * KLEN + t] = kt / norm;
}

// ---------------------------------------------------------------------------
// K2: W (fp32) -> bf16 bits
// ---------------------------------------------------------------------------
__global__ void w2bf_kernel(const float* __restrict__ W,
                            unsigned short* __restrict__ Wb, int n) {
  int i = blockIdx.x * blockDim.x + threadIdx.x;
  if (i < n) Wb[i] = f2bf(W[i]);
}

// ---------------------------------------------------------------------------
// K3: depthwise causal 512-tap FIR via block-Toeplitz MFMA.
// su now XOR-swizzled (byte ^= ((byte>>7)&3)<<4, involution: bits 4,5 ^= 7,8)
// to break the 16-bank conflict on the stride-64B B-fragment ds_read_b128.
// Same swizzle applied on writes (reg-staged) and reads.
// ---------------------------------------------------------------------------
__device__ __forceinline__ int suswz(int b) { return b ^ (((b >> 7) & 3) << 4); }

__global__ __launch_bounds__(256) void conv_kernel(
    const float* __restrict__ u, const float* __restrict__ kk,
    const float* __restrict__ D, unsigned short* __restrict__ g) {
  __shared__ __align__(16) unsigned short Apk[34 * 512];  // fragment-packed A
  __shared__ __align__(16) unsigned short su[512 + LL];   // bf16 u row, left pad
  __shared__ __align__(16) float skk[KLEN];               // fp32 k row

  const int h = blockIdx.x;
  const int tid = threadIdx.x;
  const int w = tid >> 6;
  const int ln = tid & 63;
  const int n = ln & 31;        // MFMA col (block index i)
  const int q = ln >> 5;        // k-half selector
  char* sub = (char*)su;

  // stage normalized kernel row
  if (tid < 128) *(float4*)(skk + tid * 4) = *(const float4*)(kk + (size_t)h * KLEN + tid * 4);
  __syncthreads();

  // build fragment-packed Toeplitz A: Apk[s*512 + lane*8 + j] = A[m][16s+q*8+j]
#pragma unroll 4
  for (int e = 0; e < 68; ++e) {
    int idx = e * 256 + tid;
    int s = idx >> 9;
    int lane = (idx >> 3) & 63;
    int j = idx & 7;
    int m = lane & 31, q2 = lane >> 5;
    int c = ((s & 1) << 4) + (q2 << 3) + j;
    int t = ((s >> 1) << 5) + m - c;
    Apk[idx] = (t >= 0 && t < KLEN) ? f2bf(skk[t]) : (unsigned short)0;
  }

  const float Dh = D[h];
  // byte base of B-fragment reads (pre-swizzle)
  const int bbyte0 = 1024 + 64 * (w * 64 + n) + 16 * q;   // tile0: i0 = 64w
  const int bbyte1 = bbyte0 + 2048;                       // tile1: i0 = 64w+32

  for (int b = 0; b < NB; ++b) {
    __syncthreads();  // prev-iter su readers done (and Apk built, iter 0)
    const float* __restrict__ urow = u + ((size_t)b * HH + h) * LL;
    if (tid < 64) {
      uint4 z; z.x = 0; z.y = 0; z.z = 0; z.w = 0;
      *(uint4*)(sub + suswz(tid * 16)) = z;
    }
#pragma unroll
    for (int r = 0; r < 8; ++r) {
      int i = r * 1024 + tid * 4;
      float4 v = *(const float4*)(urow + i);
      uint2 p;
      p.x = (unsigned)f2bf(v.x) | ((unsigned)f2bf(v.y) << 16);
      p.y = (unsigned)f2bf(v.z) | ((unsigned)f2bf(v.w) << 16);
      *(uint2*)(sub + suswz(1024 + 2 * i)) = p;
    }
    __syncthreads();

    v16f acc0, acc1;
#pragma unroll
    for (int r = 0; r < 16; ++r) { acc0[r] = 0.f; acc1[r] = 0.f; }

#pragma unroll
    for (int s = 0; s < 34; ++s) {
      const int offb = ((s & 1) << 5) - ((s >> 1) << 6);  // byte offset
      v8s af = *(const v8s*)(Apk + (s << 9) + (ln << 3));
      v8s b0 = *(const v8s*)(sub + suswz(bbyte0 + offb));
      v8s b1 = *(const v8s*)(sub + suswz(bbyte1 + offb));
      acc0 = __builtin_amdgcn_mfma_f32_32x32x16_bf16(af, b0, acc0, 0, 0, 0);
      acc1 = __builtin_amdgcn_mfma_f32_32x32x16_bf16(af, b1, acc1, 0, 0, 0);
    }

    // epilogue: C layout col=n, row=(reg&3)+8*(reg>>2)+4*q
    unsigned short* grow = g + ((size_t)b * HH + h) * LL;
#pragma unroll
    for (int t = 0; t < 2; ++t) {
      const int i0 = w * 64 + t * 32;
#pragma unroll
      for (int rg = 0; rg < 4; ++rg) {
        const int l = 32 * (i0 + n) + 8 * rg + 4 * q;
        float4 uu = *(const float4*)(urow + l);
        const float* up = (const float*)&uu;
        unsigned short hb[4];
#pragma unroll
        for (int rr = 0; rr < 4; ++rr) {
          float y = (t ? acc1[rg * 4 + rr] : acc0[rg * 4 + rr]) + Dh * up[rr];
          float ge = 0.5f * y * (1.0f + erff(y * 0.70710678118654752f));
          hb[rr] = f2bf(ge);
        }
        uint2 p;
        p.x = (unsigned)hb[0] | ((unsigned)hb[1] << 16);
        p.y = (unsigned)hb[2] | ((unsigned)hb[3] << 16);
        *(uint2*)(grow + l) = p;
      }
    }
  }
}

// ---------------------------------------------------------------------------
// K5: out[b][o][l] = sum_h W[o][h] * g[b][h][l] + bias[o]
// Single raw s_barrier per K-step, counted vmcnt (never 0 in loop):
//   in flight across each barrier: gll16 A(kk+1) (issued this iter, L2-resident
//   W, ~1-iter window) and B regs G(kk+2) (2-iter window > HBM latency).
// sA: logical [128][32] bf16, swizzle byte^=((byte>>7)&3)<<4 applied by
//   pre-swizzling the gll16 GLOBAL source (LDS dest stays linear, rule #21).
// sB: [kq=4][l=128][p=4] u32 of (k,k+1) bf16 pairs, swizzle
//   byte^=((byte>>7)&7)<<4 -> frag reads 4x ds_read_b128 conflict-free,
//   staging writes 2-way (free).
// ---------------------------------------------------------------------------
__device__ __forceinline__ void gll16(const void* g, void* l) {
  __builtin_amdgcn_global_load_lds(
      (const __attribute__((address_space(1))) unsigned int*)g,
      (__attribute__((address_space(3))) unsigned int*)l, 16, 0, 0);
}

__global__ __launch_bounds__(256) void gemm_kernel(
    const unsigned short* __restrict__ A,   // W bf16 [1024][1024]
    const unsigned short* __restrict__ G,   // g bf16 [4][1024][8192]
    const float* __restrict__ bias, float* __restrict__ out) {
  __shared__ __align__(16) unsigned short sA[2][4096];
  __shared__ __align__(16) unsigned int   sB[2][2048];
  const int tid = threadIdx.x;
  const int wv = tid >> 6, ln = tid & 63;

  // bijective XCD swizzle (2048 % 8 == 0): nt-grouped so the 8 mt-blocks
  // sharing a B tile are consecutive logical ids on ONE XCD.
  const int bid0 = blockIdx.x;
  const int swz = (bid0 & 7) * 256 + (bid0 >> 3);
  const int mt = swz & 7, nt = swz >> 3;
  const int o0 = mt * 128;
  const int bb = nt >> 6;             // batch index
  const int l0 = (nt & 63) * 128;     // l-tile base
  const int m16 = ln & 15, q4 = ln >> 4;
  const int wm = wv & 1, wn = wv >> 1;

  v4f acc[4][4];
#pragma unroll
  for (int i = 0; i < 4; i++)
#pragma unroll
    for (int j = 0; j < 4; j++) {
      v4f z = {0.f, 0.f, 0.f, 0.f};
      acc[i][j] = z;
    }

  // ---- A staging: 8 slots of 16 rows; wave wv covers slots 2wv, 2wv+1.
  // Pre-swizzled global source column so linear gll16 dest == swizzled layout.
  const unsigned short* gA[2];
  int lA[2];
  {
    const int cc = (((ln & 3) ^ ((ln >> 3) & 3)) << 3);
#pragma unroll
    for (int qq = 0; qq < 2; qq++) {
      const int c = wv * 2 + qq;
      const int rr = c * 16 + (ln >> 2);
      gA[qq] = A + (size_t)(o0 + rr) * HH + cc;
      lA[qq] = c * 512;
    }
  }

  // ---- B staging: thread -> (pr = k-pair 0..15, seg = l-octet 0..15)
  const int pr = tid >> 4, seg = tid & 15;
  const unsigned short* gB0 = G + ((size_t)bb * HH + 2 * pr) * LL + l0 + seg * 8;
  const unsigned short* gB1 = gB0 + LL;
  int wby[8];
#pragma unroll
  for (int e = 0; e < 8; e++) {
    int l = seg * 8 + e;
    int byi = (pr >> 2) * 2048 + l * 16 + (pr & 3) * 4;
    wby[e] = byi ^ (((l >> 3) & 7) << 4);
  }

  // ---- fragment read byte offsets
  int aby[4], bby[4];
#pragma unroll
  for (int i = 0; i < 4; i++) {
    int row = wm * 64 + i * 16 + m16;
    aby[i] = (row * 64 + q4 * 16) ^ (((m16 >> 1) & 3) << 4);
  }
#pragma unroll
  for (int j = 0; j < 4; j++) {
    int l = wn * 64 + j * 16 + m16;
    bby[j] = (q4 * 2048 + l * 16) ^ (((l >> 3) & 7) << 4);
  }

  // ---- helpers
  auto stageA = [&](int buf, int kbase) {
#pragma unroll
    for (int qq = 0; qq < 2; qq++) gll16(gA[qq] + kbase, &sA[buf][lA[qq]]);
  };
  auto packB = [&](int buf, const uint4& r0, const uint4& r1) {
    union { uint4 u; unsigned short s[8]; } ua, ub; ua.u = r0; ub.u = r1;
    char* base = (char*)sB[buf];
#pragma unroll
    for (int e = 0; e < 8; e++) {
      unsigned v = (unsigned)ua.s[e] | ((unsigned)ub.s[e] << 16);
      *(unsigned*)(base + wby[e]) = v;
    }
  };

  // ---- prologue: stage k-step 0, prefetch B(1) to stay in flight
  uint4 p0, p1, c0, c1;
  stageA(0, 0);                                     // gll16 x2 (per wave)
  __builtin_amdgcn_sched_barrier(0);
  p0 = *(const uint4*)(gB0); p1 = *(const uint4*)(gB1);          // G(0) x2
  __builtin_amdgcn_sched_barrier(0);
  c0 = *(const uint4*)(gB0 + (size_t)32 * LL);                    // G(1) x2
  c1 = *(const uint4*)(gB1 + (size_t)32 * LL);
  __builtin_amdgcn_sched_barrier(0);
  packB(0, p0, p1);                                 // compiler waits p0/p1
  asm volatile("s_waitcnt vmcnt(2) lgkmcnt(0)" ::: "memory");  // gll16+G(0) done
  __builtin_amdgcn_s_barrier();

  // ---- main loop: kk = 0..29 (steady state), peel 30, 31
  for (int kk = 0; kk < 30; ++kk) {
    const int p = kk & 1;
    // a: fragment reads of current buffers
    v8s af[4], bf4[4];
    const char* ab = (const char*)sA[p];
    const char* bbc = (const char*)sB[p];
#pragma unroll
    for (int i = 0; i < 4; i++) af[i] = *(const v8s*)(ab + aby[i]);
#pragma unroll
    for (int j = 0; j < 4; j++) bf4[j] = *(const v8s*)(bbc + bby[j]);
    // b: stage A(kk+1) into the other buffer (readers finished last iter)
    stageA(p ^ 1, (kk + 1) * 32);
    __builtin_amdgcn_sched_barrier(0);   // pin VMEM order: gll16 before B loads
    // c: B register loads for kk+2 (2-iter in-flight window)
    uint4 n0 = *(const uint4*)(gB0 + (size_t)(kk + 2) * 32 * LL);
    uint4 n1 = *(const uint4*)(gB1 + (size_t)(kk + 2) * 32 * LL);
    // d/e: MFMA on current buffers
    asm volatile("s_waitcnt lgkmcnt(0)" ::: "memory");
    __builtin_amdgcn_sched_barrier(0);
    __builtin_amdgcn_s_setprio(1);
#pragma unroll
    for (int i = 0; i < 4; i++)
#pragma unroll
      for (int j = 0; j < 4; j++)
        acc[i][j] = __builtin_amdgcn_mfma_f32_16x16x32_bf16(af[i], bf4[j], acc[i][j], 0, 0, 0);
    __builtin_amdgcn_s_setprio(0);
    // f: pack B(kk+1) (loaded last iter) into the other buffer
    asm volatile("s_waitcnt vmcnt(4)" ::: "memory");  // c0/c1 landed; gll16+n in flight
    packB(p ^ 1, c0, c1);
    c0 = n0; c1 = n1;
    // g/h: A(kk+1) landed + sB writes visible, then barrier (n stays in flight)
    asm volatile("s_waitcnt vmcnt(2) lgkmcnt(0)" ::: "memory");
    __builtin_amdgcn_s_barrier();
  }

  { // kk = 30 (p=0): no more B prefetch
    v8s af[4], bf4[4];
    const char* ab = (const char*)sA[0];
    const char* bbc = (const char*)sB[0];
#pragma unroll
    for (int i = 0; i < 4; i++) af[i] = *(const v8s*)(ab + aby[i]);
#pragma unroll
    for (int j = 0; j < 4; j++) bf4[j] = *(const v8s*)(bbc + bby[j]);
    stageA(1, 31 * 32);
    asm volatile("s_waitcnt lgkmcnt(0)" ::: "memory");
    __builtin_amdgcn_sched_barrier(0);
    __builtin_amdgcn_s_setprio(1);
#pragma unroll
    for (int i = 0; i < 4; i++)
#pragma unroll
      for (int j = 0; j < 4; j++)
        acc[i][j] = __builtin_amdgcn_mfma_f32_16x16x32_bf16(af[i], bf4[j], acc[i][j], 0, 0, 0);
    __builtin_amdgcn_s_setprio(0);
    asm volatile("s_waitcnt vmcnt(2)" ::: "memory");  // G(31) regs landed
    packB(1, c0, c1);
    asm volatile("s_waitcnt vmcnt(0) lgkmcnt(0)" ::: "memory");
    __builtin_amdgcn_s_barrier();
  }
  { // kk = 31 (p=1)
    v8s af[4], bf4[4];
    const char* ab = (const char*)sA[1];
    const char* bbc = (const char*)sB[1];
#pragma unroll
    for (int i = 0; i < 4; i++) af[i] = *(const v8s*)(ab + aby[i]);
#pragma unroll
    for (int j = 0; j < 4; j++) bf4[j] = *(const v8s*)(bbc + bby[j]);
    asm volatile("s_waitcnt lgkmcnt(0)" ::: "memory");
    __builtin_amdgcn_sched_barrier(0);
    __builtin_amdgcn_s_setprio(1);
#pragma unroll
    for (int i = 0; i < 4; i++)
#pragma unroll
      for (int j = 0; j < 4; j++)
        acc[i][j] = __builtin_amdgcn_mfma_f32_16x16x32_bf16(af[i], bf4[j], acc[i][j], 0, 0, 0);
    __builtin_amdgcn_s_setprio(0);
  }

  // ---- epilogue: C write with bias
#pragma unroll
  for (int i = 0; i < 4; i++) {
    const int ob = o0 + wm * 64 + i * 16 + q4 * 4;
#pragma unroll
    for (int j = 0; j < 4; j++) {
      const int l = l0 + wn * 64 + j * 16 + m16;
#pragma unroll
      for (int r = 0; r < 4; r++) {
        const int o = ob + r;
        out[((size_t)bb * HH + o) * LL + l] = acc[i][j][r] + bias[o];
      }
    }
  }
}

// ---------------------------------------------------------------------------
extern "C" void kernel_launch(void* const* d_in, const int* in_sizes, int n_in,
                              void* d_out, int out_size, void* d_ws, size_t ws_size,
                              hipStream_t stream) {
  const float* u   = (const float*)d_in[0];
  const float* k0  = (const float*)d_in[1];
  const float* k1  = (const float*)d_in[2];
  const float* k2  = (const float*)d_in[3];
  const float* k3  = (const float*)d_in[4];
  const float* D   = (const float*)d_in[5];
  const float* W   = (const float*)d_in[6];
  const float* bia = (const float*)d_in[7];
  float* out = (float*)d_out;

  // ws layout: g bf16 (64 MiB) | k fp32 (2 MiB) | W bf16 (2 MiB)
  char* ws = (char*)d_ws;
  unsigned short* g  = (unsigned short*)ws;
  float* kws         = (float*)(ws + (size_t)67108864);
  unsigned short* Wb = (unsigned short*)(ws + (size_t)69206016);

  build_k_kernel<<<HH, 512, 0, stream>>>(k0, k1, k2, k3, kws);
  w2bf_kernel<<<(HH * HH + 255) / 256, 256, 0, stream>>>(W, Wb, HH * HH);
  conv_kernel<<<HH, 256, 0, stream>>>(u, kws, D, g);
  gemm_kernel<<<8 * 256, 256, 0, stream>>>(Wb, g, bia, out);
}

// Round 4
// 397.226 us; speedup vs baseline: 1.0238x; 1.0238x over previous
//
#include <hip/hip_runtime.h>
#include <cstdint>
#include <cstddef>

// Problem constants (Learnable_32650341384420)
#define HH 1024      // H (channels)
#define LL 8192      // L (sequence)
#define NB 4         // B (batch)
#define KD 64
#define KLEN 512     // KD * 2^(NS-1)

typedef float v4f  __attribute__((ext_vector_type(4)));
typedef float v16f __attribute__((ext_vector_type(16)));
typedef short v8s  __attribute__((ext_vector_type(8)));

__device__ __forceinline__ unsigned short f2bf(float f) {
  union { float f; unsigned int u; } x; x.f = f;
  unsigned int r = x.u + 0x7fffu + ((x.u >> 16) & 1u);
  return (unsigned short)(r >> 16);
}

__device__ __forceinline__ float bfbits2f(unsigned int hi16) {
  union { unsigned int u; float f; } x; x.u = hi16;
  return x.f;
}

// Exact-grade gelu: A&S 7.1.26 erf, |eps| <= 1.5e-7 (far below bf16 output
// quantization). ~15 VALU ops using HW rcp/exp vs ~25-30 for libm erff.
__device__ __forceinline__ float gelu_f(float y) {
  float x = y * 0.70710678118654752f;
  float ax = fabsf(x);
  float t = __builtin_amdgcn_rcpf(fmaf(0.3275911f, ax, 1.0f));
  float p = t * fmaf(t, fmaf(t, fmaf(t, fmaf(t, 1.061405429f, -1.453152027f),
                                     1.421413741f), -0.284496736f), 0.254829592f);
  float e = __expf(-x * x);
  float erfax = fmaf(-p, e, 1.0f);
  float er = copysignf(erfax, x);
  return 0.5f * y * (1.0f + er);
}

// ---------------------------------------------------------------------------
// K1: build normalized 512-tap kernel per h (fp32).
// ---------------------------------------------------------------------------
__global__ __launch_bounds__(512) void build_k_kernel(
    const float* __restrict__ k0, const float* __restrict__ k1,
    const float* __restrict__ k2, const float* __restrict__ k3,
    float* __restrict__ kout) {
  __shared__ float lk[4][KD];
  __shared__ float red[512];
  const int h = blockIdx.x;
  const int t = threadIdx.x;
  if (t < 256) {
    int i = t >> 6, j = t & 63;
    const float* src = (i == 0) ? k0 : (i == 1) ? k1 : (i == 2) ? k2 : k3;
    lk[i][j] = src[h * KD + j];
  }
  __syncthreads();
  float kt = 0.f;
#pragma unroll
  for (int i = 0; i < 4; i++) {
    int len = KD << i;
    if (t < len) {
      float inv = 1.0f / (float)(1 << i);
      float c = ((float)t + 0.5f) * inv - 0.5f;
      c = fminf(fmaxf(c, 0.0f), 63.0f);
      int lo = (int)floorf(c);
      int hi = min(lo + 1, 63);
      float w = c - (float)lo;
      float v = lk[i][lo] * (1.0f - w) + lk[i][hi] * w;
      kt += v * (float)(1 << (3 - i));
    }
  }
  red[t] = kt * kt;
  __syncthreads();
  for (int s = 256; s > 0; s >>= 1) {
    if (t < s) red[t] += red[t + s];
    __syncthreads();
  }
  float norm = sqrtf(red[0]);
  kout[h * KLEN + t] = kt / norm;
}

// ---------------------------------------------------------------------------
// K2: W (fp32) -> bf16 bits
// ---------------------------------------------------------------------------
__global__ void w2bf_kernel(const float* __restrict__ W,
                            unsigned short* __restrict__ Wb, int n) {
  int i = blockIdx.x * blockDim.x + threadIdx.x;
  if (i < n) Wb[i] = f2bf(W[i]);
}

// ---------------------------------------------------------------------------
// K3: depthwise causal 512-tap FIR via block-Toeplitz MFMA.
// Round-3 changes (re-run after infra failure):
//  - A fragments hoisted to registers (34 v8s), loaded ONCE from Apk and
//    reused across all 4 batches (-33% LDS read traffic in the hot loop).
//  - Epilogue reads u from su (LDS bf16) instead of 16 scattered global
//    float4 loads per thread per batch.
//  - gelu via fast A&S erf instead of libm erff.
// su XOR-swizzle (byte ^= ((byte>>7)&3)<<4) on both write and read sides.
// ---------------------------------------------------------------------------
__device__ __forceinline__ int suswz(int b) { return b ^ (((b >> 7) & 3) << 4); }

__global__ __launch_bounds__(256) void conv_kernel(
    const float* __restrict__ u, const float* __restrict__ kk,
    const float* __restrict__ D, unsigned short* __restrict__ g) {
  __shared__ __align__(16) unsigned short Apk[34 * 512];  // fragment-packed A
  __shared__ __align__(16) unsigned short su[512 + LL];   // bf16 u row, left pad
  __shared__ __align__(16) float skk[KLEN];               // fp32 k row

  const int h = blockIdx.x;
  const int tid = threadIdx.x;
  const int w = tid >> 6;
  const int ln = tid & 63;
  const int n = ln & 31;        // MFMA col (block index i)
  const int q = ln >> 5;        // k-half selector
  char* sub = (char*)su;

  // stage normalized kernel row
  if (tid < 128) *(float4*)(skk + tid * 4) = *(const float4*)(kk + (size_t)h * KLEN + tid * 4);
  __syncthreads();

  // build fragment-packed Toeplitz A: Apk[s*512 + lane*8 + j] = A[m][16s+q*8+j]
#pragma unroll 4
  for (int e = 0; e < 68; ++e) {
    int idx = e * 256 + tid;
    int s = idx >> 9;
    int lane = (idx >> 3) & 63;
    int j = idx & 7;
    int m = lane & 31, q2 = lane >> 5;
    int c = ((s & 1) << 4) + (q2 << 3) + j;
    int t = ((s >> 1) << 5) + m - c;
    Apk[idx] = (t >= 0 && t < KLEN) ? f2bf(skk[t]) : (unsigned short)0;
  }
  __syncthreads();  // Apk built

  // hoist A fragments to registers: constant across the 4 batches
  v8s af[34];
#pragma unroll
  for (int s = 0; s < 34; ++s)
    af[s] = *(const v8s*)(Apk + (s << 9) + (ln << 3));

  const float Dh = D[h];
  // byte base of B-fragment reads (pre-swizzle)
  const int bbyte0 = 1024 + 64 * (w * 64 + n) + 16 * q;   // tile0: i0 = 64w

  for (int b = 0; b < NB; ++b) {
    __syncthreads();  // prev-iter su readers done
    const float* __restrict__ urow = u + ((size_t)b * HH + h) * LL;
    if (tid < 64) {
      uint4 z; z.x = 0; z.y = 0; z.z = 0; z.w = 0;
      *(uint4*)(sub + suswz(tid * 16)) = z;
    }
#pragma unroll
    for (int r = 0; r < 8; ++r) {
      int i = r * 1024 + tid * 4;
      float4 v = *(const float4*)(urow + i);
      uint2 p;
      p.x = (unsigned)f2bf(v.x) | ((unsigned)f2bf(v.y) << 16);
      p.y = (unsigned)f2bf(v.z) | ((unsigned)f2bf(v.w) << 16);
      *(uint2*)(sub + suswz(1024 + 2 * i)) = p;
    }
    __syncthreads();

    v16f acc0, acc1;
#pragma unroll
    for (int r = 0; r < 16; ++r) { acc0[r] = 0.f; acc1[r] = 0.f; }

#pragma unroll
    for (int s = 0; s < 34; ++s) {
      const int offb = ((s & 1) << 5) - ((s >> 1) << 6);  // byte offset
      const char* pb = sub + suswz(bbyte0 + offb);
      v8s b0 = *(const v8s*)(pb);
      v8s b1 = *(const v8s*)(pb + 2048);   // tile1 = tile0 + 2048B (swizzle-safe)
      acc0 = __builtin_amdgcn_mfma_f32_32x32x16_bf16(af[s], b0, acc0, 0, 0, 0);
      acc1 = __builtin_amdgcn_mfma_f32_32x32x16_bf16(af[s], b1, acc1, 0, 0, 0);
    }

    // epilogue: C layout col=n, row=(reg&3)+8*(reg>>2)+4*q
    // u for the D*u term comes from su (bf16) -- no scattered global loads.
    unsigned short* grow = g + ((size_t)b * HH + h) * LL;
#pragma unroll
    for (int t = 0; t < 2; ++t) {
      const int i0 = w * 64 + t * 32;
#pragma unroll
      for (int rg = 0; rg < 4; ++rg) {
        const int l = 32 * (i0 + n) + 8 * rg + 4 * q;
        uint2 up2 = *(const uint2*)(sub + suswz(1024 + 2 * l));
        float uf[4];
        uf[0] = bfbits2f(up2.x << 16);
        uf[1] = bfbits2f(up2.x & 0xffff0000u);
        uf[2] = bfbits2f(up2.y << 16);
        uf[3] = bfbits2f(up2.y & 0xffff0000u);
        unsigned short hb[4];
#pragma unroll
        for (int rr = 0; rr < 4; ++rr) {
          float y = (t ? acc1[rg * 4 + rr] : acc0[rg * 4 + rr]) + Dh * uf[rr];
          hb[rr] = f2bf(gelu_f(y));
        }
        uint2 p;
        p.x = (unsigned)hb[0] | ((unsigned)hb[1] << 16);
        p.y = (unsigned)hb[2] | ((unsigned)hb[3] << 16);
        *(uint2*)(grow + l) = p;
      }
    }
  }
}

// ---------------------------------------------------------------------------
// K5: out[b][o][l] = sum_h W[o][h] * g[b][h][l] + bias[o]
// (unchanged from round 2: counted-vmcnt pipeline, swizzled sA/sB, XCD swizzle)
// ---------------------------------------------------------------------------
__device__ __forceinline__ void gll16(const void* g, void* l) {
  __builtin_amdgcn_global_load_lds(
      (const __attribute__((address_space(1))) unsigned int*)g,
      (__attribute__((address_space(3))) unsigned int*)l, 16, 0, 0);
}

__global__ __launch_bounds__(256) void gemm_kernel(
    const unsigned short* __restrict__ A,   // W bf16 [1024][1024]
    const unsigned short* __restrict__ G,   // g bf16 [4][1024][8192]
    const float* __restrict__ bias, float* __restrict__ out) {
  __shared__ __align__(16) unsigned short sA[2][4096];
  __shared__ __align__(16) unsigned int   sB[2][2048];
  const int tid = threadIdx.x;
  const int wv = tid >> 6, ln = tid & 63;

  const int bid0 = blockIdx.x;
  const int swz = (bid0 & 7) * 256 + (bid0 >> 3);
  const int mt = swz & 7, nt = swz >> 3;
  const int o0 = mt * 128;
  const int bb = nt >> 6;             // batch index
  const int l0 = (nt & 63) * 128;     // l-tile base
  const int m16 = ln & 15, q4 = ln >> 4;
  const int wm = wv & 1, wn = wv >> 1;

  v4f acc[4][4];
#pragma unroll
  for (int i = 0; i < 4; i++)
#pragma unroll
    for (int j = 0; j < 4; j++) {
      v4f z = {0.f, 0.f, 0.f, 0.f};
      acc[i][j] = z;
    }

  const unsigned short* gA[2];
  int lA[2];
  {
    const int cc = (((ln & 3) ^ ((ln >> 3) & 3)) << 3);
#pragma unroll
    for (int qq = 0; qq < 2; qq++) {
      const int c = wv * 2 + qq;
      const int rr = c * 16 + (ln >> 2);
      gA[qq] = A + (size_t)(o0 + rr) * HH + cc;
      lA[qq] = c * 512;
    }
  }

  const int pr = tid >> 4, seg = tid & 15;
  const unsigned short* gB0 = G + ((size_t)bb * HH + 2 * pr) * LL + l0 + seg * 8;
  const unsigned short* gB1 = gB0 + LL;
  int wby[8];
#pragma unroll
  for (int e = 0; e < 8; e++) {
    int l = seg * 8 + e;
    int byi = (pr >> 2) * 2048 + l * 16 + (pr & 3) * 4;
    wby[e] = byi ^ (((l >> 3) & 7) << 4);
  }

  int aby[4], bby[4];
#pragma unroll
  for (int i = 0; i < 4; i++) {
    int row = wm * 64 + i * 16 + m16;
    aby[i] = (row * 64 + q4 * 16) ^ (((m16 >> 1) & 3) << 4);
  }
#pragma unroll
  for (int j = 0; j < 4; j++) {
    int l = wn * 64 + j * 16 + m16;
    bby[j] = (q4 * 2048 + l * 16) ^ (((l >> 3) & 7) << 4);
  }

  auto stageA = [&](int buf, int kbase) {
#pragma unroll
    for (int qq = 0; qq < 2; qq++) gll16(gA[qq] + kbase, &sA[buf][lA[qq]]);
  };
  auto packB = [&](int buf, const uint4& r0, const uint4& r1) {
    union { uint4 u; unsigned short s[8]; } ua, ub; ua.u = r0; ub.u = r1;
    char* base = (char*)sB[buf];
#pragma unroll
    for (int e = 0; e < 8; e++) {
      unsigned v = (unsigned)ua.s[e] | ((unsigned)ub.s[e] << 16);
      *(unsigned*)(base + wby[e]) = v;
    }
  };

  uint4 p0, p1, c0, c1;
  stageA(0, 0);
  __builtin_amdgcn_sched_barrier(0);
  p0 = *(const uint4*)(gB0); p1 = *(const uint4*)(gB1);
  __builtin_amdgcn_sched_barrier(0);
  c0 = *(const uint4*)(gB0 + (size_t)32 * LL);
  c1 = *(const uint4*)(gB1 + (size_t)32 * LL);
  __builtin_amdgcn_sched_barrier(0);
  packB(0, p0, p1);
  asm volatile("s_waitcnt vmcnt(2) lgkmcnt(0)" ::: "memory");
  __builtin_amdgcn_s_barrier();

  for (int kk = 0; kk < 30; ++kk) {
    const int p = kk & 1;
    v8s af[4], bf4[4];
    const char* ab = (const char*)sA[p];
    const char* bbc = (const char*)sB[p];
#pragma unroll
    for (int i = 0; i < 4; i++) af[i] = *(const v8s*)(ab + aby[i]);
#pragma unroll
    for (int j = 0; j < 4; j++) bf4[j] = *(const v8s*)(bbc + bby[j]);
    stageA(p ^ 1, (kk + 1) * 32);
    __builtin_amdgcn_sched_barrier(0);
    uint4 n0 = *(const uint4*)(gB0 + (size_t)(kk + 2) * 32 * LL);
    uint4 n1 = *(const uint4*)(gB1 + (size_t)(kk + 2) * 32 * LL);
    asm volatile("s_waitcnt lgkmcnt(0)" ::: "memory");
    __builtin_amdgcn_sched_barrier(0);
    __builtin_amdgcn_s_setprio(1);
#pragma unroll
    for (int i = 0; i < 4; i++)
#pragma unroll
      for (int j = 0; j < 4; j++)
        acc[i][j] = __builtin_amdgcn_mfma_f32_16x16x32_bf16(af[i], bf4[j], acc[i][j], 0, 0, 0);
    __builtin_amdgcn_s_setprio(0);
    asm volatile("s_waitcnt vmcnt(4)" ::: "memory");
    packB(p ^ 1, c0, c1);
    c0 = n0; c1 = n1;
    asm volatile("s_waitcnt vmcnt(2) lgkmcnt(0)" ::: "memory");
    __builtin_amdgcn_s_barrier();
  }

  { // kk = 30 (p=0)
    v8s af[4], bf4[4];
    const char* ab = (const char*)sA[0];
    const char* bbc = (const char*)sB[0];
#pragma unroll
    for (int i = 0; i < 4; i++) af[i] = *(const v8s*)(ab + aby[i]);
#pragma unroll
    for (int j = 0; j < 4; j++) bf4[j] = *(const v8s*)(bbc + bby[j]);
    stageA(1, 31 * 32);
    asm volatile("s_waitcnt lgkmcnt(0)" ::: "memory");
    __builtin_amdgcn_sched_barrier(0);
    __builtin_amdgcn_s_setprio(1);
#pragma unroll
    for (int i = 0; i < 4; i++)
#pragma unroll
      for (int j = 0; j < 4; j++)
        acc[i][j] = __builtin_amdgcn_mfma_f32_16x16x32_bf16(af[i], bf4[j], acc[i][j], 0, 0, 0);
    __builtin_amdgcn_s_setprio(0);
    asm volatile("s_waitcnt vmcnt(2)" ::: "memory");
    packB(1, c0, c1);
    asm volatile("s_waitcnt vmcnt(0) lgkmcnt(0)" ::: "memory");
    __builtin_amdgcn_s_barrier();
  }
  { // kk = 31 (p=1)
    v8s af[4], bf4[4];
    const char* ab = (const char*)sA[1];
    const char* bbc = (const char*)sB[1];
#pragma unroll
    for (int i = 0; i < 4; i++) af[i] = *(const v8s*)(ab + aby[i]);
#pragma unroll
    for (int j = 0; j < 4; j++) bf4[j] = *(const v8s*)(bbc + bby[j]);
    asm volatile("s_waitcnt lgkmcnt(0)" ::: "memory");
    __builtin_amdgcn_sched_barrier(0);
    __builtin_amdgcn_s_setprio(1);
#pragma unroll
    for (int i = 0; i < 4; i++)
#pragma unroll
      for (int j = 0; j < 4; j++)
        acc[i][j] = __builtin_amdgcn_mfma_f32_16x16x32_bf16(af[i], bf4[j], acc[i][j], 0, 0, 0);
    __builtin_amdgcn_s_setprio(0);
  }

#pragma unroll
  for (int i = 0; i < 4; i++) {
    const int ob = o0 + wm * 64 + i * 16 + q4 * 4;
#pragma unroll
    for (int j = 0; j < 4; j++) {
      const int l = l0 + wn * 64 + j * 16 + m16;
#pragma unroll
      for (int r = 0; r < 4; r++) {
        const int o = ob + r;
        out[((size_t)bb * HH + o) * LL + l] = acc[i][j][r] + bias[o];
      }
    }
  }
}

// ---------------------------------------------------------------------------
extern "C" void kernel_launch(void* const* d_in, const int* in_sizes, int n_in,
                              void* d_out, int out_size, void* d_ws, size_t ws_size,
                              hipStream_t stream) {
  const float* u   = (const float*)d_in[0];
  const float* k0  = (const float*)d_in[1];
  const float* k1  = (const float*)d_in[2];
  const float* k2  = (const float*)d_in[3];
  const float* k3  = (const float*)d_in[4];
  const float* D   = (const float*)d_in[5];
  const float* W   = (const float*)d_in[6];
  const float* bia = (const float*)d_in[7];
  float* out = (float*)d_out;

  // ws layout: g bf16 (64 MiB) | k fp32 (2 MiB) | W bf16 (2 MiB)
  char* ws = (char*)d_ws;
  unsigned short* g  = (unsigned short*)ws;
  float* kws         = (float*)(ws + (size_t)67108864);
  unsigned short* Wb = (unsigned short*)(ws + (size_t)69206016);

  build_k_kernel<<<HH, 512, 0, stream>>>(k0, k1, k2, k3, kws);
  w2bf_kernel<<<(HH * HH + 255) / 256, 256, 0, stream>>>(W, Wb, HH * HH);
  conv_kernel<<<HH, 256, 0, stream>>>(u, kws, D, g);
  gemm_kernel<<<8 * 256, 256, 0, stream>>>(Wb, g, bia, out);
}

// Round 5
// 375.394 us; speedup vs baseline: 1.0834x; 1.0582x over previous
//
#include <hip/hip_runtime.h>
#include <cstdint>
#include <cstddef>

// Problem constants (Learnable_32650341384420)
#define HH 1024      // H (channels)
#define LL 8192      // L (sequence)
#define NB 4         // B (batch)
#define KD 64
#define KLEN 512     // KD * 2^(NS-1)
#define LHALF 4096   // conv L-split per block

typedef float v4f  __attribute__((ext_vector_type(4)));
typedef float v16f __attribute__((ext_vector_type(16)));
typedef short v8s  __attribute__((ext_vector_type(8)));

__device__ __forceinline__ unsigned short f2bf(float f) {
  union { float f; unsigned int u; } x; x.f = f;
  unsigned int r = x.u + 0x7fffu + ((x.u >> 16) & 1u);
  return (unsigned short)(r >> 16);
}

__device__ __forceinline__ float bfbits2f(unsigned int hi16) {
  union { unsigned int u; float f; } x; x.u = hi16;
  return x.f;
}

// Exact-grade gelu: A&S 7.1.26 erf, |eps| <= 1.5e-7 (far below bf16 output
// quantization). ~15 VALU ops using HW rcp/exp vs ~25-30 for libm erff.
__device__ __forceinline__ float gelu_f(float y) {
  float x = y * 0.70710678118654752f;
  float ax = fabsf(x);
  float t = __builtin_amdgcn_rcpf(fmaf(0.3275911f, ax, 1.0f));
  float p = t * fmaf(t, fmaf(t, fmaf(t, fmaf(t, 1.061405429f, -1.453152027f),
                                     1.421413741f), -0.284496736f), 0.254829592f);
  float e = __expf(-x * x);
  float erfax = fmaf(-p, e, 1.0f);
  float er = copysignf(erfax, x);
  return 0.5f * y * (1.0f + er);
}

// ---------------------------------------------------------------------------
// K1: build normalized 512-tap kernel per h (fp32).
// ---------------------------------------------------------------------------
__global__ __launch_bounds__(512) void build_k_kernel(
    const float* __restrict__ k0, const float* __restrict__ k1,
    const float* __restrict__ k2, const float* __restrict__ k3,
    float* __restrict__ kout) {
  __shared__ float lk[4][KD];
  __shared__ float red[512];
  const int h = blockIdx.x;
  const int t = threadIdx.x;
  if (t < 256) {
    int i = t >> 6, j = t & 63;
    const float* src = (i == 0) ? k0 : (i == 1) ? k1 : (i == 2) ? k2 : k3;
    lk[i][j] = src[h * KD + j];
  }
  __syncthreads();
  float kt = 0.f;
#pragma unroll
  for (int i = 0; i < 4; i++) {
    int len = KD << i;
    if (t < len) {
      float inv = 1.0f / (float)(1 << i);
      float c = ((float)t + 0.5f) * inv - 0.5f;
      c = fminf(fmaxf(c, 0.0f), 63.0f);
      int lo = (int)floorf(c);
      int hi = min(lo + 1, 63);
      float w = c - (float)lo;
      float v = lk[i][lo] * (1.0f - w) + lk[i][hi] * w;
      kt += v * (float)(1 << (3 - i));
    }
  }
  red[t] = kt * kt;
  __syncthreads();
  for (int s = 256; s > 0; s >>= 1) {
    if (t < s) red[t] += red[t + s];
    __syncthreads();
  }
  float norm = sqrtf(red[0]);
  kout[h * KLEN + t] = kt / norm;
}

// ---------------------------------------------------------------------------
// K2: W (fp32) -> bf16 bits
// ---------------------------------------------------------------------------
__global__ void w2bf_kernel(const float* __restrict__ W,
                            unsigned short* __restrict__ Wb, int n) {
  int i = blockIdx.x * blockDim.x + threadIdx.x;
  if (i < n) Wb[i] = f2bf(W[i]);
}

// ---------------------------------------------------------------------------
// K3: depthwise causal 512-tap FIR via block-Toeplitz MFMA.
// Round-5: occupancy-first restructure.
//  - af-hoist REVERTED (round 4: 1 block/CU, OccupancyPercent 10.5%).
//    A fragments re-read from Apk per s (84-VGPR regime).
//  - L split in half per block: grid 2048 = (h, half). su shrinks to
//    512-pad + 4096 -> LDS 46 KB -> 3 blocks/CU, 8 blocks of work per CU.
//  - One 32x32 output tile per wave (acc = 16 VGPR, single MFMA chain).
//  - Kept from round 4: fast gelu, epilogue u from LDS.
// su XOR-swizzle (byte ^= ((byte>>7)&3)<<4) on both write and read sides.
// ---------------------------------------------------------------------------
__device__ __forceinline__ int suswz(int b) { return b ^ (((b >> 7) & 3) << 4); }

__global__ __launch_bounds__(256) void conv_kernel(
    const float* __restrict__ u, const float* __restrict__ kk,
    const float* __restrict__ D, unsigned short* __restrict__ g) {
  __shared__ __align__(16) unsigned short Apk[34 * 512];     // 34816 B
  __shared__ __align__(16) unsigned short su[512 + LHALF];   // 9216 B
  __shared__ __align__(16) float skk[KLEN];                  // 2048 B

  const int bid = blockIdx.x;
  const int h = bid >> 1;
  const int half = bid & 1;
  const int l0 = half * LHALF;
  const int tid = threadIdx.x;
  const int w = tid >> 6;
  const int ln = tid & 63;
  const int n = ln & 31;        // MFMA col (output I-block index within tile)
  const int q = ln >> 5;        // k-half selector
  char* sub = (char*)su;

  // stage normalized kernel row
  if (tid < 128) *(float4*)(skk + tid * 4) = *(const float4*)(kk + (size_t)h * KLEN + tid * 4);
  __syncthreads();

  // build fragment-packed Toeplitz A: Apk[s*512 + lane*8 + j] = A[m][16s+q*8+j]
#pragma unroll 4
  for (int e = 0; e < 68; ++e) {
    int idx = e * 256 + tid;
    int s = idx >> 9;
    int lane = (idx >> 3) & 63;
    int j = idx & 7;
    int m = lane & 31, q2 = lane >> 5;
    int c = ((s & 1) << 4) + (q2 << 3) + j;
    int t = ((s >> 1) << 5) + m - c;
    Apk[idx] = (t >= 0 && t < KLEN) ? f2bf(skk[t]) : (unsigned short)0;
  }

  const float Dh = D[h];
  // byte base of B-fragment reads (pre-swizzle): elem 512 + 32*(w*32+n) + 8q
  const int bbyte0 = 1024 + 64 * (w * 32 + n) + 16 * q;

  for (int b = 0; b < NB; ++b) {
    __syncthreads();  // prev-iter su readers done (and Apk built, iter 0)
    const float* __restrict__ urow = u + ((size_t)b * HH + h) * LL;
    // pad region: u history [l0-512, l0) (zeros for half 0)
    if (tid < 128) {
      int i = tid * 4;
      uint2 p;
      if (half == 0) {
        p.x = 0u; p.y = 0u;
      } else {
        float4 v = *(const float4*)(urow + l0 - 512 + i);
        p.x = (unsigned)f2bf(v.x) | ((unsigned)f2bf(v.y) << 16);
        p.y = (unsigned)f2bf(v.z) | ((unsigned)f2bf(v.w) << 16);
      }
      *(uint2*)(sub + suswz(2 * i)) = p;
    }
    // main region: u[l0, l0+4096)
#pragma unroll
    for (int r = 0; r < 4; ++r) {
      int i = r * 1024 + tid * 4;
      float4 v = *(const float4*)(urow + l0 + i);
      uint2 p;
      p.x = (unsigned)f2bf(v.x) | ((unsigned)f2bf(v.y) << 16);
      p.y = (unsigned)f2bf(v.z) | ((unsigned)f2bf(v.w) << 16);
      *(uint2*)(sub + suswz(1024 + 2 * i)) = p;
    }
    __syncthreads();

    v16f acc;
#pragma unroll
    for (int r = 0; r < 16; ++r) acc[r] = 0.f;

#pragma unroll
    for (int s = 0; s < 34; ++s) {
      const int offb = ((s & 1) << 5) - ((s >> 1) << 6);  // byte offset
      v8s af = *(const v8s*)(Apk + (s << 9) + (ln << 3));
      v8s b0 = *(const v8s*)(sub + suswz(bbyte0 + offb));
      acc = __builtin_amdgcn_mfma_f32_32x32x16_bf16(af, b0, acc, 0, 0, 0);
    }

    // epilogue: C layout col=n, row=(reg&3)+8*(reg>>2)+4*q
    // u for the D*u term comes from su (bf16) -- no scattered global loads.
    unsigned short* grow = g + ((size_t)b * HH + h) * LL + l0;
#pragma unroll
    for (int rg = 0; rg < 4; ++rg) {
      const int l = 32 * (w * 32 + n) + 8 * rg + 4 * q;
      uint2 up2 = *(const uint2*)(sub + suswz(1024 + 2 * l));
      float uf[4];
      uf[0] = bfbits2f(up2.x << 16);
      uf[1] = bfbits2f(up2.x & 0xffff0000u);
      uf[2] = bfbits2f(up2.y << 16);
      uf[3] = bfbits2f(up2.y & 0xffff0000u);
      unsigned short hb[4];
#pragma unroll
      for (int rr = 0; rr < 4; ++rr) {
        float y = acc[rg * 4 + rr] + Dh * uf[rr];
        hb[rr] = f2bf(gelu_f(y));
      }
      uint2 p;
      p.x = (unsigned)hb[0] | ((unsigned)hb[1] << 16);
      p.y = (unsigned)hb[2] | ((unsigned)hb[3] << 16);
      *(uint2*)(grow + l) = p;
    }
  }
}

// ---------------------------------------------------------------------------
// K5: out[b][o][l] = sum_h W[o][h] * g[b][h][l] + bias[o]
// (unchanged: counted-vmcnt pipeline, swizzled sA/sB, XCD swizzle)
// ---------------------------------------------------------------------------
__device__ __forceinline__ void gll16(const void* g, void* l) {
  __builtin_amdgcn_global_load_lds(
      (const __attribute__((address_space(1))) unsigned int*)g,
      (__attribute__((address_space(3))) unsigned int*)l, 16, 0, 0);
}

__global__ __launch_bounds__(256) void gemm_kernel(
    const unsigned short* __restrict__ A,   // W bf16 [1024][1024]
    const unsigned short* __restrict__ G,   // g bf16 [4][1024][8192]
    const float* __restrict__ bias, float* __restrict__ out) {
  __shared__ __align__(16) unsigned short sA[2][4096];
  __shared__ __align__(16) unsigned int   sB[2][2048];
  const int tid = threadIdx.x;
  const int wv = tid >> 6, ln = tid & 63;

  const int bid0 = blockIdx.x;
  const int swz = (bid0 & 7) * 256 + (bid0 >> 3);
  const int mt = swz & 7, nt = swz >> 3;
  const int o0 = mt * 128;
  const int bb = nt >> 6;             // batch index
  const int l0 = (nt & 63) * 128;     // l-tile base
  const int m16 = ln & 15, q4 = ln >> 4;
  const int wm = wv & 1, wn = wv >> 1;

  v4f acc[4][4];
#pragma unroll
  for (int i = 0; i < 4; i++)
#pragma unroll
    for (int j = 0; j < 4; j++) {
      v4f z = {0.f, 0.f, 0.f, 0.f};
      acc[i][j] = z;
    }

  const unsigned short* gA[2];
  int lA[2];
  {
    const int cc = (((ln & 3) ^ ((ln >> 3) & 3)) << 3);
#pragma unroll
    for (int qq = 0; qq < 2; qq++) {
      const int c = wv * 2 + qq;
      const int rr = c * 16 + (ln >> 2);
      gA[qq] = A + (size_t)(o0 + rr) * HH + cc;
      lA[qq] = c * 512;
    }
  }

  const int pr = tid >> 4, seg = tid & 15;
  const unsigned short* gB0 = G + ((size_t)bb * HH + 2 * pr) * LL + l0 + seg * 8;
  const unsigned short* gB1 = gB0 + LL;
  int wby[8];
#pragma unroll
  for (int e = 0; e < 8; e++) {
    int l = seg * 8 + e;
    int byi = (pr >> 2) * 2048 + l * 16 + (pr & 3) * 4;
    wby[e] = byi ^ (((l >> 3) & 7) << 4);
  }

  int aby[4], bby[4];
#pragma unroll
  for (int i = 0; i < 4; i++) {
    int row = wm * 64 + i * 16 + m16;
    aby[i] = (row * 64 + q4 * 16) ^ (((m16 >> 1) & 3) << 4);
  }
#pragma unroll
  for (int j = 0; j < 4; j++) {
    int l = wn * 64 + j * 16 + m16;
    bby[j] = (q4 * 2048 + l * 16) ^ (((l >> 3) & 7) << 4);
  }

  auto stageA = [&](int buf, int kbase) {
#pragma unroll
    for (int qq = 0; qq < 2; qq++) gll16(gA[qq] + kbase, &sA[buf][lA[qq]]);
  };
  auto packB = [&](int buf, const uint4& r0, const uint4& r1) {
    union { uint4 u; unsigned short s[8]; } ua, ub; ua.u = r0; ub.u = r1;
    char* base = (char*)sB[buf];
#pragma unroll
    for (int e = 0; e < 8; e++) {
      unsigned v = (unsigned)ua.s[e] | ((unsigned)ub.s[e] << 16);
      *(unsigned*)(base + wby[e]) = v;
    }
  };

  uint4 p0, p1, c0, c1;
  stageA(0, 0);
  __builtin_amdgcn_sched_barrier(0);
  p0 = *(const uint4*)(gB0); p1 = *(const uint4*)(gB1);
  __builtin_amdgcn_sched_barrier(0);
  c0 = *(const uint4*)(gB0 + (size_t)32 * LL);
  c1 = *(const uint4*)(gB1 + (size_t)32 * LL);
  __builtin_amdgcn_sched_barrier(0);
  packB(0, p0, p1);
  asm volatile("s_waitcnt vmcnt(2) lgkmcnt(0)" ::: "memory");
  __builtin_amdgcn_s_barrier();

  for (int kk = 0; kk < 30; ++kk) {
    const int p = kk & 1;
    v8s af[4], bf4[4];
    const char* ab = (const char*)sA[p];
    const char* bbc = (const char*)sB[p];
#pragma unroll
    for (int i = 0; i < 4; i++) af[i] = *(const v8s*)(ab + aby[i]);
#pragma unroll
    for (int j = 0; j < 4; j++) bf4[j] = *(const v8s*)(bbc + bby[j]);
    stageA(p ^ 1, (kk + 1) * 32);
    __builtin_amdgcn_sched_barrier(0);
    uint4 n0 = *(const uint4*)(gB0 + (size_t)(kk + 2) * 32 * LL);
    uint4 n1 = *(const uint4*)(gB1 + (size_t)(kk + 2) * 32 * LL);
    asm volatile("s_waitcnt lgkmcnt(0)" ::: "memory");
    __builtin_amdgcn_sched_barrier(0);
    __builtin_amdgcn_s_setprio(1);
#pragma unroll
    for (int i = 0; i < 4; i++)
#pragma unroll
      for (int j = 0; j < 4; j++)
        acc[i][j] = __builtin_amdgcn_mfma_f32_16x16x32_bf16(af[i], bf4[j], acc[i][j], 0, 0, 0);
    __builtin_amdgcn_s_setprio(0);
    asm volatile("s_waitcnt vmcnt(4)" ::: "memory");
    packB(p ^ 1, c0, c1);
    c0 = n0; c1 = n1;
    asm volatile("s_waitcnt vmcnt(2) lgkmcnt(0)" ::: "memory");
    __builtin_amdgcn_s_barrier();
  }

  { // kk = 30 (p=0)
    v8s af[4], bf4[4];
    const char* ab = (const char*)sA[0];
    const char* bbc = (const char*)sB[0];
#pragma unroll
    for (int i = 0; i < 4; i++) af[i] = *(const v8s*)(ab + aby[i]);
#pragma unroll
    for (int j = 0; j < 4; j++) bf4[j] = *(const v8s*)(bbc + bby[j]);
    stageA(1, 31 * 32);
    asm volatile("s_waitcnt lgkmcnt(0)" ::: "memory");
    __builtin_amdgcn_sched_barrier(0);
    __builtin_amdgcn_s_setprio(1);
#pragma unroll
    for (int i = 0; i < 4; i++)
#pragma unroll
      for (int j = 0; j < 4; j++)
        acc[i][j] = __builtin_amdgcn_mfma_f32_16x16x32_bf16(af[i], bf4[j], acc[i][j], 0, 0, 0);
    __builtin_amdgcn_s_setprio(0);
    asm volatile("s_waitcnt vmcnt(2)" ::: "memory");
    packB(1, c0, c1);
    asm volatile("s_waitcnt vmcnt(0) lgkmcnt(0)" ::: "memory");
    __builtin_amdgcn_s_barrier();
  }
  { // kk = 31 (p=1)
    v8s af[4], bf4[4];
    const char* ab = (const char*)sA[1];
    const char* bbc = (const char*)sB[1];
#pragma unroll
    for (int i = 0; i < 4; i++) af[i] = *(const v8s*)(ab + aby[i]);
#pragma unroll
    for (int j = 0; j < 4; j++) bf4[j] = *(const v8s*)(bbc + bby[j]);
    asm volatile("s_waitcnt lgkmcnt(0)" ::: "memory");
    __builtin_amdgcn_sched_barrier(0);
    __builtin_amdgcn_s_setprio(1);
#pragma unroll
    for (int i = 0; i < 4; i++)
#pragma unroll
      for (int j = 0; j < 4; j++)
        acc[i][j] = __builtin_amdgcn_mfma_f32_16x16x32_bf16(af[i], bf4[j], acc[i][j], 0, 0, 0);
    __builtin_amdgcn_s_setprio(0);
  }

#pragma unroll
  for (int i = 0; i < 4; i++) {
    const int ob = o0 + wm * 64 + i * 16 + q4 * 4;
#pragma unroll
    for (int j = 0; j < 4; j++) {
      const int l = l0 + wn * 64 + j * 16 + m16;
#pragma unroll
      for (int r = 0; r < 4; r++) {
        const int o = ob + r;
        out[((size_t)bb * HH + o) * LL + l] = acc[i][j][r] + bias[o];
      }
    }
  }
}

// ---------------------------------------------------------------------------
extern "C" void kernel_launch(void* const* d_in, const int* in_sizes, int n_in,
                              void* d_out, int out_size, void* d_ws, size_t ws_size,
                              hipStream_t stream) {
  const float* u   = (const float*)d_in[0];
  const float* k0  = (const float*)d_in[1];
  const float* k1  = (const float*)d_in[2];
  const float* k2  = (const float*)d_in[3];
  const float* k3  = (const float*)d_in[4];
  const float* D   = (const float*)d_in[5];
  const float* W   = (const float*)d_in[6];
  const float* bia = (const float*)d_in[7];
  float* out = (float*)d_out;

  // ws layout: g bf16 (64 MiB) | k fp32 (2 MiB) | W bf16 (2 MiB)
  char* ws = (char*)d_ws;
  unsigned short* g  = (unsigned short*)ws;
  float* kws         = (float*)(ws + (size_t)67108864);
  unsigned short* Wb = (unsigned short*)(ws + (size_t)69206016);

  build_k_kernel<<<HH, 512, 0, stream>>>(k0, k1, k2, k3, kws);
  w2bf_kernel<<<(HH * HH + 255) / 256, 256, 0, stream>>>(W, Wb, HH * HH);
  conv_kernel<<<HH * 2, 256, 0, stream>>>(u, kws, D, g);
  gemm_kernel<<<8 * 256, 256, 0, stream>>>(Wb, g, bia, out);
}